// Round 4
// baseline (2678.126 us; speedup 1.0000x reference)
//
#include <hip/hip_runtime.h>

// IntersiteModel fused — round 4: 4 threads per sample, w-axis split.
// Round-3 post-mortem: per-thread accumulator state (~240 live floats at peak)
// can never fit a wave's register budget -> 334 MB scratch spill traffic,
// VALUBusy 26%. Fix is structural: split every output-channel (w) dimension
// across Q=4 threads. Per-thread accs: t0:8, t1:12, u0:16, u1:24 floats.
// Shared per-sample state in LDS (stride 180 floats: odd*4 -> conflict-free
// across the 8 samples per half-wave, 16B aligned). 32 samples/block,
// LDS = 32*180*4 = 23040 B -> 7 blocks/CU. Cross-thread handoff via
// __syncthreads(); final 4-lane reduction via __shfl_xor (lanes 4s..4s+3
// are always in one wave).
//
// LDS slot layout (per sample, feature index f):
//   staging:  f 0..39 site1 (x0[16], x1[8][3]) | f 40..79 site2 | f 80..95 edge
//   stage1+:  f 96..127 t0[32] | f 128..175 t1[16][3]
//   stage3:   f 0..31 s | f 32..63 g | f 64..159 v[32][3]  (x/y/e/t dead)

#define TPB 128
#define SPB 32           // samples per block (TPB/4)
#define STRIDE 180       // floats per sample slot

__device__ __forceinline__ float sigf(float x) {
    return 1.0f / (1.0f + __expf(-x));
}

__global__ __launch_bounds__(TPB, 3)
void intersite_fused(const float* __restrict__ site1,
                     const float* __restrict__ site2,
                     const float* __restrict__ edge,
                     const float* __restrict__ W1_00,
                     const float* __restrict__ W1_11_0,
                     const float* __restrict__ W1_01,
                     const float* __restrict__ W1_10,
                     const float* __restrict__ W1_11_1,
                     const float* __restrict__ W2_00,
                     const float* __restrict__ W2_11_0,
                     const float* __restrict__ W2_01,
                     const float* __restrict__ W2_10,
                     const float* __restrict__ W2_11_1,
                     const float* __restrict__ W3_00,
                     const float* __restrict__ W3_11,
                     float* __restrict__ out, int B)
{
    __shared__ float lds[SPB * STRIDE];
    const int t  = threadIdx.x;
    const int q  = t & 3;        // w-slice owner within sample
    const int sL = t >> 2;       // local sample
    const int sg = blockIdx.x * SPB + sL;

#define L(f) lds[sL * STRIDE + (f)]

    const float inv_s3   = 0.57735026918962576f;  // 1/sqrt(3)
    const float inv_s2   = 0.70710678118654752f;  // 1/sqrt(2)
    const float inv_s320 = 0.05590169943749474f;  // 1/sqrt(320)
    const float inv_s192 = 0.07216878364870323f;  // 1/sqrt(192)
    const float inv_s256 = 0.0625f;               // 1/sqrt(256)
    const float inv_s2048= 0.02209708691207961f;  // 1/sqrt(2048)

    // ---------------- phase A: coalesced staging ----------------
    {
        const float4* g1 = (const float4*)site1;
        const float4* g2 = (const float4*)site2;
        const int blk0 = blockIdx.x * SPB * 10;       // float4 units (40/4)
        #pragma unroll
        for (int rr = 0; rr < 3; ++rr) {
            int r = t + rr * TPB;
            if (r < SPB * 10) {
                int G = blk0 + r;
                if (G * 4 < B * 40) {
                    int smp = r / 10, f = (r % 10) * 4;
                    float4 a = g1[G];
                    float* p = &lds[smp * STRIDE + f];
                    p[0]=a.x; p[1]=a.y; p[2]=a.z; p[3]=a.w;
                    float4 c = g2[G];
                    float* p2 = &lds[smp * STRIDE + 40 + f];
                    p2[0]=c.x; p2[1]=c.y; p2[2]=c.z; p2[3]=c.w;
                }
            }
        }
        const float4* ge = (const float4*)edge;
        int r = t;                                    // 128 float4 per block
        int G = blockIdx.x * SPB * 4 + r;
        if (G * 4 < B * 16) {
            int smp = r / 4, f = 80 + (r % 4) * 4;
            float4 a = ge[G];
            float* p = &lds[smp * STRIDE + f];
            p[0]=a.x; p[1]=a.y; p[2]=a.z; p[3]=a.w;
        }
    }
    __syncthreads();

    // ---------------- stage 1: (x,y) -> t0 slice[8], t1 slice[4 vec] -------
    float y0r[16];
    #pragma unroll
    for (int v = 0; v < 16; ++v) y0r[v] = L(40 + v);
    float y1r[24];
    #pragma unroll
    for (int v = 0; v < 8; ++v)
        #pragma unroll
        for (int i = 0; i < 3; ++i) y1r[v*3+i] = L(56 + v*3 + i);

    float t0R[8];
    #pragma unroll
    for (int k = 0; k < 8; ++k) t0R[k] = 0.0f;

    // W1_00 (16,16,32), w-slice [8q,8q+8)
    #pragma unroll 1
    for (int u = 0; u < 16; ++u) {
        float xu = L(u);
        const float* w = W1_00 + u*512 + 8*q;
        #pragma unroll
        for (int v = 0; v < 16; ++v) {
            float f = xu * y0r[v];
            #pragma unroll
            for (int k = 0; k < 8; ++k) t0R[k] = fmaf(f, w[v*32+k], t0R[k]);
        }
    }

    float t1v[12];
    #pragma unroll
    for (int j = 0; j < 12; ++j) t1v[j] = 0.0f;

    // W1_11_0 (8,8,32) [t0 slice 8] + W1_11_1 (8,8,16) [t1 slice 4], merged
    #pragma unroll 1
    for (int u = 0; u < 8; ++u) {
        float ax = L(16+u*3), ay = L(17+u*3), az = L(18+u*3);
        const float* w0 = W1_11_0 + u*256 + 8*q;
        const float* w1 = W1_11_1 + u*128 + 4*q;
        #pragma unroll
        for (int v = 0; v < 8; ++v) {
            float bx = y1r[v*3], by = y1r[v*3+1], bz = y1r[v*3+2];
            float d = (ax*bx + ay*by + az*bz) * inv_s3;
            #pragma unroll
            for (int k = 0; k < 8; ++k) t0R[k] = fmaf(d, w0[v*32+k], t0R[k]);
            float cx = (ay*bz - az*by) * inv_s2;
            float cy = (az*bx - ax*bz) * inv_s2;
            float cz = (ax*by - ay*bx) * inv_s2;
            #pragma unroll
            for (int k = 0; k < 4; ++k) {
                float wv = w1[v*16+k];
                t1v[k*3+0] = fmaf(cx, wv, t1v[k*3+0]);
                t1v[k*3+1] = fmaf(cy, wv, t1v[k*3+1]);
                t1v[k*3+2] = fmaf(cz, wv, t1v[k*3+2]);
            }
        }
    }
    #pragma unroll
    for (int k = 0; k < 8; ++k) t0R[k] *= inv_s320;

    // W1_01 (16,8,16): A[v][k] = sum_u x0[u] W[u,v,4q+k]; t1 += A*y1
    {
        float A[32];
        #pragma unroll
        for (int j = 0; j < 32; ++j) A[j] = 0.0f;
        #pragma unroll 1
        for (int u = 0; u < 16; ++u) {
            float xu = L(u);
            const float* w = W1_01 + u*128 + 4*q;
            #pragma unroll
            for (int v = 0; v < 8; ++v)
                #pragma unroll
                for (int k = 0; k < 4; ++k)
                    A[v*4+k] = fmaf(xu, w[v*16+k], A[v*4+k]);
        }
        #pragma unroll
        for (int v = 0; v < 8; ++v)
            #pragma unroll
            for (int k = 0; k < 4; ++k)
                #pragma unroll
                for (int i = 0; i < 3; ++i)
                    t1v[k*3+i] = fmaf(A[v*4+k], y1r[v*3+i], t1v[k*3+i]);
    }
    // W1_10 (8,16,16): Bm[u][k] = sum_v y0[v] W[u,v,4q+k]; t1 += Bm*x1
    {
        float Bm[32];
        #pragma unroll
        for (int j = 0; j < 32; ++j) Bm[j] = 0.0f;
        #pragma unroll 1
        for (int v = 0; v < 16; ++v) {
            float yv = y0r[v];
            const float* w = W1_10 + v*16 + 4*q;
            #pragma unroll
            for (int u = 0; u < 8; ++u)
                #pragma unroll
                for (int k = 0; k < 4; ++k)
                    Bm[u*4+k] = fmaf(yv, w[u*256+k], Bm[u*4+k]);
        }
        #pragma unroll
        for (int u = 0; u < 8; ++u) {
            float ax = L(16+u*3), ay = L(17+u*3), az = L(18+u*3);
            #pragma unroll
            for (int k = 0; k < 4; ++k) {
                float m = Bm[u*4+k];
                t1v[k*3+0] = fmaf(m, ax, t1v[k*3+0]);
                t1v[k*3+1] = fmaf(m, ay, t1v[k*3+1]);
                t1v[k*3+2] = fmaf(m, az, t1v[k*3+2]);
            }
        }
    }
    #pragma unroll
    for (int j = 0; j < 12; ++j) t1v[j] *= inv_s320;

    // publish t slices
    #pragma unroll
    for (int k = 0; k < 8; ++k) L(96 + 8*q + k) = t0R[k];
    #pragma unroll
    for (int k = 0; k < 4; ++k)
        #pragma unroll
        for (int i = 0; i < 3; ++i) L(128 + (4*q+k)*3 + i) = t1v[k*3+i];
    __syncthreads();

    // ---------------- stage 2 ----------------
    float e0r[4], e1r[12];
    #pragma unroll
    for (int v = 0; v < 4; ++v) e0r[v] = L(80 + v);
    #pragma unroll
    for (int j = 0; j < 12; ++j) e1r[j] = L(84 + j);

    // u0 slice [16q,16q+16): W2_00 (32,4,64) then W2_11_0 (16,4,64)
    float u0a[16];
    #pragma unroll
    for (int k = 0; k < 16; ++k) u0a[k] = 0.0f;
    #pragma unroll 1
    for (int u = 0; u < 32; ++u) {
        float tu = L(96 + u);
        const float* wa = W2_00 + u*256 + 16*q;
        #pragma unroll
        for (int v = 0; v < 4; ++v) {
            float f = tu * e0r[v];
            #pragma unroll
            for (int k = 0; k < 16; ++k) u0a[k] = fmaf(f, wa[v*64+k], u0a[k]);
        }
    }
    #pragma unroll 1
    for (int u = 0; u < 16; ++u) {
        float ax = L(128+u*3), ay = L(129+u*3), az = L(130+u*3);
        const float* w0 = W2_11_0 + u*256 + 16*q;
        #pragma unroll
        for (int v = 0; v < 4; ++v) {
            float d = (ax*e1r[v*3] + ay*e1r[v*3+1] + az*e1r[v*3+2]) * inv_s3;
            #pragma unroll
            for (int k = 0; k < 16; ++k) u0a[k] = fmaf(d, w0[v*64+k], u0a[k]);
        }
    }
    // activation + publish s/g (u0a dies here, before u1 accs go live)
    if (q < 2) {
        #pragma unroll
        for (int k = 0; k < 16; ++k) {
            float x = u0a[k] * inv_s192;
            L(16*q + k) = x * sigf(x);            // s channels 0..31
        }
    } else {
        #pragma unroll
        for (int k = 0; k < 16; ++k) {
            float x = u0a[k] * inv_s192;
            L(32 + 16*(q-2) + k) = sigf(x);       // gate channels 0..31
        }
    }

    // u1 slice [8q,8q+8): W2_01 factored, W2_10, W2_11_1
    float u1a[24];
    #pragma unroll
    for (int j = 0; j < 24; ++j) u1a[j] = 0.0f;
    {
        float A2[32];                              // A2[v][k], k<8
        #pragma unroll
        for (int j = 0; j < 32; ++j) A2[j] = 0.0f;
        #pragma unroll 1
        for (int u = 0; u < 32; ++u) {
            float tu = L(96 + u);
            const float* w = W2_01 + u*128 + 8*q;
            #pragma unroll
            for (int v = 0; v < 4; ++v)
                #pragma unroll
                for (int k = 0; k < 8; ++k)
                    A2[v*8+k] = fmaf(tu, w[v*32+k], A2[v*8+k]);
        }
        #pragma unroll 1
        for (int u = 0; u < 16; ++u) {
            float ax = L(128+u*3), ay = L(129+u*3), az = L(130+u*3);
            const float* wc = W2_10   + u*128 + 8*q;
            const float* wx = W2_11_1 + u*128 + 8*q;
            float C[8];
            #pragma unroll
            for (int k = 0; k < 8; ++k) C[k] = 0.0f;
            #pragma unroll
            for (int v = 0; v < 4; ++v) {
                float bx = e1r[v*3], by = e1r[v*3+1], bz = e1r[v*3+2];
                #pragma unroll
                for (int k = 0; k < 8; ++k) C[k] = fmaf(e0r[v], wc[v*32+k], C[k]);
                float cx = (ay*bz - az*by) * inv_s2;
                float cy = (az*bx - ax*bz) * inv_s2;
                float cz = (ax*by - ay*bx) * inv_s2;
                #pragma unroll
                for (int k = 0; k < 8; ++k) {
                    float wv = wx[v*32+k];
                    u1a[k*3+0] = fmaf(cx, wv, u1a[k*3+0]);
                    u1a[k*3+1] = fmaf(cy, wv, u1a[k*3+1]);
                    u1a[k*3+2] = fmaf(cz, wv, u1a[k*3+2]);
                }
            }
            #pragma unroll
            for (int k = 0; k < 8; ++k) {
                u1a[k*3+0] = fmaf(ax, C[k], u1a[k*3+0]);
                u1a[k*3+1] = fmaf(ay, C[k], u1a[k*3+1]);
                u1a[k*3+2] = fmaf(az, C[k], u1a[k*3+2]);
            }
        }
        #pragma unroll
        for (int v = 0; v < 4; ++v)
            #pragma unroll
            for (int k = 0; k < 8; ++k)
                #pragma unroll
                for (int i = 0; i < 3; ++i)
                    u1a[k*3+i] = fmaf(A2[v*8+k], e1r[v*3+i], u1a[k*3+i]);
    }
    __syncthreads();   // all t reads done; s/g published

    // ---------------- stage 3: gate, publish v (overwrites t region) ------
    #pragma unroll
    for (int k = 0; k < 8; ++k) {
        float gw = L(32 + 8*q + k) * inv_s256;     // g[w] * 1/sqrt(256)
        L(64 + (8*q+k)*3 + 0) = u1a[k*3+0] * gw;
        L(64 + (8*q+k)*3 + 1) = u1a[k*3+1] * gw;
        L(64 + (8*q+k)*3 + 2) = u1a[k*3+2] * gw;
    }
    __syncthreads();

    // tensor square, v2-slice [8q,8q+8)
    float acc0 = 0.0f;
    {
        float zs[8];
        #pragma unroll
        for (int k = 0; k < 8; ++k) zs[k] = 0.0f;
        #pragma unroll 1
        for (int u = 0; u < 32; ++u) {
            float su = L(u);
            const float* w = W3_00 + u*32 + 8*q;
            #pragma unroll
            for (int k = 0; k < 8; ++k) zs[k] = fmaf(su, w[k], zs[k]);
        }
        #pragma unroll
        for (int k = 0; k < 8; ++k) acc0 = fmaf(zs[k], L(8*q + k), acc0);
    }
    float acc1 = 0.0f;
    #pragma unroll
    for (int i = 0; i < 3; ++i) {
        float zv[8];
        #pragma unroll
        for (int k = 0; k < 8; ++k) zv[k] = 0.0f;
        #pragma unroll 1
        for (int u = 0; u < 32; ++u) {
            float vu = L(64 + u*3 + i);
            const float* w = W3_11 + u*32 + 8*q;
            #pragma unroll
            for (int k = 0; k < 8; ++k) zv[k] = fmaf(vu, w[k], zv[k]);
        }
        #pragma unroll
        for (int k = 0; k < 8; ++k) acc1 = fmaf(zv[k], L(64 + (8*q+k)*3 + i), acc1);
    }

    float total = (acc0 + acc1 * inv_s3) * inv_s2048;
    total += __shfl_xor(total, 1);
    total += __shfl_xor(total, 2);
    if (q == 0 && sg < B) out[sg] = total;
#undef L
}

extern "C" void kernel_launch(void* const* d_in, const int* in_sizes, int n_in,
                              void* d_out, int out_size, void* d_ws, size_t ws_size,
                              hipStream_t stream)
{
    const float* site1   = (const float*)d_in[0];
    const float* site2   = (const float*)d_in[1];
    const float* edge    = (const float*)d_in[2];
    const float* W1_00   = (const float*)d_in[3];
    const float* W1_11_0 = (const float*)d_in[4];
    const float* W1_01   = (const float*)d_in[5];
    const float* W1_10   = (const float*)d_in[6];
    const float* W1_11_1 = (const float*)d_in[7];
    const float* W2_00   = (const float*)d_in[8];
    const float* W2_11_0 = (const float*)d_in[9];
    const float* W2_01   = (const float*)d_in[10];
    const float* W2_10   = (const float*)d_in[11];
    const float* W2_11_1 = (const float*)d_in[12];
    const float* W3_00   = (const float*)d_in[13];
    const float* W3_11   = (const float*)d_in[14];
    float* out = (float*)d_out;

    const int B = in_sizes[0] / 40;
    dim3 grid((B + SPB - 1) / SPB), block(TPB);
    hipLaunchKernelGGL(intersite_fused, grid, block, 0, stream,
                       site1, site2, edge,
                       W1_00, W1_11_0, W1_01, W1_10, W1_11_1,
                       W2_00, W2_11_0, W2_01, W2_10, W2_11_1,
                       W3_00, W3_11, out, B);
}